// Round 1
// baseline (617.907 us; speedup 1.0000x reference)
//
#include <hip/hip_runtime.h>
#include <math.h>

// Problem constants (compile-time; shapes are fixed by the reference)
#define B 2
#define L 2048
#define D 1024
#define H 16
#define HD 64
#define W 32
#define M (B * L)   // 4096 rows

// ---------------- conn kernel (tiny) ----------------
__global__ __launch_bounds__(512) void conn_kernel(
    const float* __restrict__ cw1, const float* __restrict__ cw2,
    const float* __restrict__ cw3, float* __restrict__ conn)
{
    __shared__ float vals[H][W];
    const int t = threadIdx.x;          // 512 = H*W
    const int h = t >> 5;
    const int w = t & 31;
    const float pos = (float)w / (float)(W - 1);
    float s = 0.f;
    for (int k = 0; k < 128; ++k) {
        const float a1 = pos * cw1[h * 128 + k];
        const float a3 = pos * cw3[h * 128 + k];
        const float si = a1 / (1.f + expf(-a1));   // silu
        s += si * a3 * cw2[h * 128 + k];
    }
    vals[h][w] = s;
    __syncthreads();
    float mx = -1e30f;
    for (int i = 0; i < W; ++i) mx = fmaxf(mx, vals[h][i]);
    float den = 0.f;
    for (int i = 0; i < W; ++i) den += expf(vals[h][i] - mx);
    conn[t] = expf(s - mx) / den;
}

// ---------------- GEMM config ----------------
// C[M,N] = A[M,K] * Wt[N,K]^T   (both K-major in memory -> coalesced K loads)
#define BM 128
#define BN 128
#define BK 16
// 256 threads, 8x8 microtile each (16x16 thread grid)

// ---------------- fused QKV + RoPE ----------------
__global__ __launch_bounds__(256) void qkv_kernel(
    const float* __restrict__ x,
    const float* __restrict__ wq, const float* __restrict__ wk,
    const float* __restrict__ wv,
    const float* __restrict__ rope_cos, const float* __restrict__ rope_sin,
    float* __restrict__ qb, float* __restrict__ kb, float* __restrict__ vb)
{
    __shared__ float As[BK][BM + 4];
    __shared__ float Bs[BK][BN + 4];
    const int tid = threadIdx.x;
    const int tx = tid & 15;
    const int ty = tid >> 4;
    const int bx = blockIdx.x;               // 0..23 : 3 weights x 8 col-tiles
    const int m0 = blockIdx.y * BM;
    const int which = bx >> 3;               // 0=Q 1=K 2=V
    const float* Wg = (which == 0) ? wq : ((which == 1) ? wk : wv);
    float* dst = (which == 0) ? qb : ((which == 1) ? kb : vb);
    const int n0 = (bx & 7) * BN;

    const int r = tid >> 2;                  // 0..63 tile row
    const int kq = (tid & 3) << 2;           // float4 col within BK

    const float* Ap = x + (size_t)(m0 + r) * D + kq;
    const float* Bp = Wg + (size_t)(n0 + r) * D + kq;

    float4 a0 = *(const float4*)(Ap);
    float4 a1 = *(const float4*)(Ap + (size_t)64 * D);
    float4 b0 = *(const float4*)(Bp);
    float4 b1 = *(const float4*)(Bp + (size_t)64 * D);

    float acc[8][8];
#pragma unroll
    for (int i = 0; i < 8; ++i)
#pragma unroll
        for (int j = 0; j < 8; ++j) acc[i][j] = 0.f;

    const int KT = D / BK;                   // 64
    for (int kt = 0; kt < KT; ++kt) {
        __syncthreads();
        As[kq + 0][r] = a0.x; As[kq + 1][r] = a0.y; As[kq + 2][r] = a0.z; As[kq + 3][r] = a0.w;
        As[kq + 0][r + 64] = a1.x; As[kq + 1][r + 64] = a1.y; As[kq + 2][r + 64] = a1.z; As[kq + 3][r + 64] = a1.w;
        Bs[kq + 0][r] = b0.x; Bs[kq + 1][r] = b0.y; Bs[kq + 2][r] = b0.z; Bs[kq + 3][r] = b0.w;
        Bs[kq + 0][r + 64] = b1.x; Bs[kq + 1][r + 64] = b1.y; Bs[kq + 2][r + 64] = b1.z; Bs[kq + 3][r + 64] = b1.w;
        __syncthreads();
        if (kt + 1 < KT) {
            const float* Ap2 = Ap + (kt + 1) * BK;
            const float* Bp2 = Bp + (kt + 1) * BK;
            a0 = *(const float4*)(Ap2);
            a1 = *(const float4*)(Ap2 + (size_t)64 * D);
            b0 = *(const float4*)(Bp2);
            b1 = *(const float4*)(Bp2 + (size_t)64 * D);
        }
#pragma unroll
        for (int kk = 0; kk < BK; ++kk) {
            float ar[8], br[8];
            *(float4*)&ar[0] = *(const float4*)&As[kk][ty * 8];
            *(float4*)&ar[4] = *(const float4*)&As[kk][ty * 8 + 4];
            *(float4*)&br[0] = *(const float4*)&Bs[kk][tx * 8];
            *(float4*)&br[4] = *(const float4*)&Bs[kk][tx * 8 + 4];
#pragma unroll
            for (int i = 0; i < 8; ++i)
#pragma unroll
                for (int j = 0; j < 8; ++j)
                    acc[i][j] = fmaf(ar[i], br[j], acc[i][j]);
        }
    }

    // Epilogue: RoPE (Q,K) and scatter to [b][h][l][hd]
    const int cb = n0 + tx * 8;              // e base; 8-aligned -> same head
    const int h = cb >> 6;
    const int hdb = cb & 63;
#pragma unroll
    for (int i = 0; i < 8; ++i) {
        const int m = m0 + ty * 8 + i;
        const int bb = m >> 11;              // / L
        const int l = m & (L - 1);
        float o[8];
        if (which < 2) {
#pragma unroll
            for (int p = 0; p < 4; ++p) {
                const int ip = (hdb >> 1) + p;      // rope pair index
                const float c = rope_cos[l * (HD / 2) + ip];
                const float s = rope_sin[l * (HD / 2) + ip];
                const float t0 = acc[i][2 * p], t1 = acc[i][2 * p + 1];
                o[2 * p]     = t0 * c - t1 * s;
                o[2 * p + 1] = t0 * s + t1 * c;
            }
        } else {
#pragma unroll
            for (int j = 0; j < 8; ++j) o[j] = acc[i][j];
        }
        float* pd = dst + (((size_t)(bb * H + h) * L + l) * HD + hdb);
        *(float4*)(pd)     = make_float4(o[0], o[1], o[2], o[3]);
        *(float4*)(pd + 4) = make_float4(o[4], o[5], o[6], o[7]);
    }
}

// ---------------- sliding-window attention ----------------
#define QT 64
#define KR (QT + W - 1)    // 95 staged K/V rows
#define KP 68              // padded row length (floats): 2-way max bank aliasing

__global__ __launch_bounds__(64) void attn_kernel(
    const float* __restrict__ qb, const float* __restrict__ kb,
    const float* __restrict__ vb, const float* __restrict__ conn,
    float* __restrict__ ao)
{
    __shared__ float Ks[KR][KP];
    __shared__ float Vs[KR][KP];
    __shared__ float Ss[QT][W + 1];          // per-query scores (avoids reg-array scratch)
    const int tid = threadIdx.x;             // 64 = one wave, one query each
    const int l0 = blockIdx.x * QT;
    const int bh = blockIdx.y;               // b*H + h
    const int h = bh & (H - 1);
    const int bb = bh >> 4;
    const float* Qg = qb + (size_t)bh * L * HD;
    const float* Kg = kb + (size_t)bh * L * HD;
    const float* Vg = vb + (size_t)bh * L * HD;

    // stage K/V rows [l0-31 .. l0+63]; out-of-range rows are zeros (matches
    // the reference's zero padding: their scores are exactly 0 and INCLUDED
    // in the softmax)
    for (int idx = tid; idx < KR * 16; idx += 64) {
        const int rr = idx >> 4;
        const int f4 = (idx & 15) << 2;
        const int lr = l0 - (W - 1) + rr;
        float4 kv = make_float4(0, 0, 0, 0);
        float4 vv = make_float4(0, 0, 0, 0);
        if (lr >= 0) {
            kv = *(const float4*)(Kg + (size_t)lr * HD + f4);
            vv = *(const float4*)(Vg + (size_t)lr * HD + f4);
        }
        *(float4*)&Ks[rr][f4] = kv;
        *(float4*)&Vs[rr][f4] = vv;
    }
    __syncthreads();

    const int l = l0 + tid;
    float4 q[16];
#pragma unroll
    for (int i = 0; i < 16; ++i) q[i] = *(const float4*)(Qg + (size_t)l * HD + i * 4);

    // scores -> Ss
    for (int w = 0; w < W; ++w) {
        const float* kr = Ks[tid + w];
        float s = 0.f;
#pragma unroll
        for (int i = 0; i < 16; ++i) {
            const float4 kv = *(const float4*)(kr + i * 4);
            s = fmaf(q[i].x, kv.x, s);
            s = fmaf(q[i].y, kv.y, s);
            s = fmaf(q[i].z, kv.z, s);
            s = fmaf(q[i].w, kv.w, s);
        }
        Ss[tid][w] = s * 0.125f;             // / sqrt(64)
    }

    float mx = -1e30f;
    for (int w = 0; w < W; ++w) mx = fmaxf(mx, Ss[tid][w]);
    float den = 0.f;
    for (int w = 0; w < W; ++w) {
        const float e = expf(Ss[tid][w] - mx);
        den += e;
        Ss[tid][w] = e;
    }
    const float inv = 1.f / den;
    float fsum = 0.f;
    for (int w = 0; w < W; ++w) {
        const float fw = Ss[tid][w] * inv * conn[h * W + w];  // attn * conn
        fsum += fw;
        Ss[tid][w] = fw;
    }
    const float rn = 1.f / (fsum + 1e-9f);   // same order as reference

    float4 o[16];
#pragma unroll
    for (int i = 0; i < 16; ++i) o[i] = make_float4(0, 0, 0, 0);
    for (int w = 0; w < W; ++w) {
        const float wt = Ss[tid][w] * rn;
        const float* vr = Vs[tid + w];
#pragma unroll
        for (int i = 0; i < 16; ++i) {
            const float4 vv = *(const float4*)(vr + i * 4);
            o[i].x = fmaf(wt, vv.x, o[i].x);
            o[i].y = fmaf(wt, vv.y, o[i].y);
            o[i].z = fmaf(wt, vv.z, o[i].z);
            o[i].w = fmaf(wt, vv.w, o[i].w);
        }
    }
    // store to [b][l][h*64+hd] so the output projection is a plain GEMM
    float* dst = ao + ((size_t)(bb * L + l) * D + h * HD);
#pragma unroll
    for (int i = 0; i < 16; ++i) *(float4*)(dst + i * 4) = o[i];
}

// ---------------- output projection ----------------
__global__ __launch_bounds__(256) void out_kernel(
    const float* __restrict__ a, const float* __restrict__ wo,
    float* __restrict__ out)
{
    __shared__ float As[BK][BM + 4];
    __shared__ float Bs[BK][BN + 4];
    const int tid = threadIdx.x;
    const int tx = tid & 15;
    const int ty = tid >> 4;
    const int n0 = blockIdx.x * BN;
    const int m0 = blockIdx.y * BM;

    const int r = tid >> 2;
    const int kq = (tid & 3) << 2;
    const float* Ap = a + (size_t)(m0 + r) * D + kq;
    const float* Bp = wo + (size_t)(n0 + r) * D + kq;

    float4 a0 = *(const float4*)(Ap);
    float4 a1 = *(const float4*)(Ap + (size_t)64 * D);
    float4 b0 = *(const float4*)(Bp);
    float4 b1 = *(const float4*)(Bp + (size_t)64 * D);

    float acc[8][8];
#pragma unroll
    for (int i = 0; i < 8; ++i)
#pragma unroll
        for (int j = 0; j < 8; ++j) acc[i][j] = 0.f;

    const int KT = D / BK;
    for (int kt = 0; kt < KT; ++kt) {
        __syncthreads();
        As[kq + 0][r] = a0.x; As[kq + 1][r] = a0.y; As[kq + 2][r] = a0.z; As[kq + 3][r] = a0.w;
        As[kq + 0][r + 64] = a1.x; As[kq + 1][r + 64] = a1.y; As[kq + 2][r + 64] = a1.z; As[kq + 3][r + 64] = a1.w;
        Bs[kq + 0][r] = b0.x; Bs[kq + 1][r] = b0.y; Bs[kq + 2][r] = b0.z; Bs[kq + 3][r] = b0.w;
        Bs[kq + 0][r + 64] = b1.x; Bs[kq + 1][r + 64] = b1.y; Bs[kq + 2][r + 64] = b1.z; Bs[kq + 3][r + 64] = b1.w;
        __syncthreads();
        if (kt + 1 < KT) {
            const float* Ap2 = Ap + (kt + 1) * BK;
            const float* Bp2 = Bp + (kt + 1) * BK;
            a0 = *(const float4*)(Ap2);
            a1 = *(const float4*)(Ap2 + (size_t)64 * D);
            b0 = *(const float4*)(Bp2);
            b1 = *(const float4*)(Bp2 + (size_t)64 * D);
        }
#pragma unroll
        for (int kk = 0; kk < BK; ++kk) {
            float ar[8], br[8];
            *(float4*)&ar[0] = *(const float4*)&As[kk][ty * 8];
            *(float4*)&ar[4] = *(const float4*)&As[kk][ty * 8 + 4];
            *(float4*)&br[0] = *(const float4*)&Bs[kk][tx * 8];
            *(float4*)&br[4] = *(const float4*)&Bs[kk][tx * 8 + 4];
#pragma unroll
            for (int i = 0; i < 8; ++i)
#pragma unroll
                for (int j = 0; j < 8; ++j)
                    acc[i][j] = fmaf(ar[i], br[j], acc[i][j]);
        }
    }

#pragma unroll
    for (int i = 0; i < 8; ++i) {
        const int m = m0 + ty * 8 + i;
        float* pd = out + (size_t)m * D + n0 + tx * 8;
        *(float4*)(pd)     = make_float4(acc[i][0], acc[i][1], acc[i][2], acc[i][3]);
        *(float4*)(pd + 4) = make_float4(acc[i][4], acc[i][5], acc[i][6], acc[i][7]);
    }
}

// ---------------- launcher ----------------
extern "C" void kernel_launch(void* const* d_in, const int* in_sizes, int n_in,
                              void* d_out, int out_size, void* d_ws, size_t ws_size,
                              hipStream_t stream)
{
    const float* x   = (const float*)d_in[0];
    const float* wq  = (const float*)d_in[1];
    const float* wk  = (const float*)d_in[2];
    const float* wv  = (const float*)d_in[3];
    const float* wo  = (const float*)d_in[4];
    const float* cw1 = (const float*)d_in[5];
    const float* cw2 = (const float*)d_in[6];
    const float* cw3 = (const float*)d_in[7];
    const float* rc  = (const float*)d_in[8];
    const float* rs  = (const float*)d_in[9];
    float* out = (float*)d_out;

    float* ws   = (float*)d_ws;
    float* conn = ws;                         // 512 floats
    float* qb   = ws + 1024;                  // [B][H][L][HD]
    float* kb   = qb + (size_t)M * D;
    float* vb   = kb + (size_t)M * D;
    float* ao   = vb + (size_t)M * D;         // [B][L][D]

    conn_kernel<<<dim3(1), dim3(512), 0, stream>>>(cw1, cw2, cw3, conn);
    qkv_kernel<<<dim3(24, 32), dim3(256), 0, stream>>>(x, wq, wk, wv, rc, rs, qb, kb, vb);
    attn_kernel<<<dim3(L / QT, B * H), dim3(64), 0, stream>>>(qb, kb, vb, conn, ao);
    out_kernel<<<dim3(8, 32), dim3(256), 0, stream>>>(ao, wo, out);
}

// Round 2
// 398.642 us; speedup vs baseline: 1.5500x; 1.5500x over previous
//
#include <hip/hip_runtime.h>
#include <math.h>

#define B 2
#define L 2048
#define D 1024
#define H 16
#define HD 64
#define W 32
#define M (B * L)          // 4096
#define KP3 3072           // packed K' = 3*D

typedef unsigned short ushort_t;
typedef short bf16x8 __attribute__((ext_vector_type(8)));
typedef float f32x4 __attribute__((ext_vector_type(4)));

static __device__ __forceinline__ unsigned short f2bf(float f) {
    union { float f; unsigned u; } v; v.f = f;
    unsigned r = v.u + 0x7FFF + ((v.u >> 16) & 1);
    return (unsigned short)(r >> 16);
}
static __device__ __forceinline__ float bf2f(unsigned short h) {
    union { unsigned u; float f; } v; v.u = ((unsigned)h) << 16;
    return v.f;
}
static __device__ __forceinline__ unsigned pk2(unsigned a, unsigned b) {
    return a | (b << 16);
}

// ---------------- packing: x -> A-side [hi | lo | hi] ----------------
__global__ __launch_bounds__(256) void pack_x_kernel(
    const float* __restrict__ src, ushort_t* __restrict__ dst)
{
    const int idx = blockIdx.x * 256 + threadIdx.x;   // M*128 threads
    const int r = idx >> 7;
    const int c = (idx & 127) << 3;
    const float* p = src + (size_t)r * D + c;
    const float4 f0 = *(const float4*)p;
    const float4 f1 = *(const float4*)(p + 4);
    float f[8] = {f0.x, f0.y, f0.z, f0.w, f1.x, f1.y, f1.z, f1.w};
    unsigned short h[8], lo[8];
#pragma unroll
    for (int i = 0; i < 8; ++i) {
        h[i] = f2bf(f[i]);
        lo[i] = f2bf(f[i] - bf2f(h[i]));
    }
    uint4 hv = make_uint4(pk2(h[0], h[1]), pk2(h[2], h[3]), pk2(h[4], h[5]), pk2(h[6], h[7]));
    uint4 lv = make_uint4(pk2(lo[0], lo[1]), pk2(lo[2], lo[3]), pk2(lo[4], lo[5]), pk2(lo[6], lo[7]));
    ushort_t* d = dst + (size_t)r * KP3 + c;
    *(uint4*)(d)        = hv;
    *(uint4*)(d + D)    = lv;   // A-side: hi | lo | hi
    *(uint4*)(d + 2 * D) = hv;
}

// ---------------- packing: weights -> B-side [hi | hi | lo] ----------------
__global__ __launch_bounds__(256) void pack_w_kernel(
    const float* __restrict__ s0, const float* __restrict__ s1,
    const float* __restrict__ s2, ushort_t* __restrict__ dst, int nrows)
{
    const int idx = blockIdx.x * 256 + threadIdx.x;
    const int r = idx >> 7;
    if (r >= nrows) return;
    const int c = (idx & 127) << 3;
    const float* src = (r < 1024) ? s0 : ((r < 2048) ? s1 : s2);
    const float* p = src + (size_t)(r & 1023) * D + c;
    const float4 f0 = *(const float4*)p;
    const float4 f1 = *(const float4*)(p + 4);
    float f[8] = {f0.x, f0.y, f0.z, f0.w, f1.x, f1.y, f1.z, f1.w};
    unsigned short h[8], lo[8];
#pragma unroll
    for (int i = 0; i < 8; ++i) {
        h[i] = f2bf(f[i]);
        lo[i] = f2bf(f[i] - bf2f(h[i]));
    }
    uint4 hv = make_uint4(pk2(h[0], h[1]), pk2(h[2], h[3]), pk2(h[4], h[5]), pk2(h[6], h[7]));
    uint4 lv = make_uint4(pk2(lo[0], lo[1]), pk2(lo[2], lo[3]), pk2(lo[4], lo[5]), pk2(lo[6], lo[7]));
    ushort_t* d = dst + (size_t)r * KP3 + c;
    *(uint4*)(d)        = hv;
    *(uint4*)(d + D)    = hv;   // B-side: hi | hi | lo
    *(uint4*)(d + 2 * D) = lv;
}

// ---------------- conn kernel (tiny) ----------------
__global__ __launch_bounds__(512) void conn_kernel(
    const float* __restrict__ cw1, const float* __restrict__ cw2,
    const float* __restrict__ cw3, float* __restrict__ conn)
{
    __shared__ float vals[H][W];
    const int t = threadIdx.x;
    const int h = t >> 5;
    const int w = t & 31;
    const float pos = (float)w / (float)(W - 1);
    float s = 0.f;
    for (int k = 0; k < 128; ++k) {
        const float a1 = pos * cw1[h * 128 + k];
        const float a3 = pos * cw3[h * 128 + k];
        const float si = a1 / (1.f + expf(-a1));
        s += si * a3 * cw2[h * 128 + k];
    }
    vals[h][w] = s;
    __syncthreads();
    float mx = -1e30f;
    for (int i = 0; i < W; ++i) mx = fmaxf(mx, vals[h][i]);
    float den = 0.f;
    for (int i = 0; i < W; ++i) den += expf(vals[h][i] - mx);
    conn[t] = expf(s - mx) / den;
}

// ---------------- split-bf16 MFMA GEMM (m97 structure) ----------------
// C[M,N] = A'[M,3072] * B'[N,3072]^T, 128x128 tile, 4 waves, BK=64.
// mode 0: plain fp32 write to outp[M][1024]
// mode 1: QKV: RoPE on Q/K, scatter to qb/kb/vb [b*H+h][l][hd]
__global__ __launch_bounds__(256) void gemm_split(
    const ushort_t* __restrict__ Ap, const ushort_t* __restrict__ Bp,
    int mode, float* __restrict__ outp,
    float* __restrict__ qb, float* __restrict__ kb, float* __restrict__ vb,
    const float* __restrict__ rc, const float* __restrict__ rs)
{
    __shared__ short As[128 * 64];
    __shared__ short Bs[128 * 64];
    const int tid = threadIdx.x;
    const int w = tid >> 6;          // wave 0..3
    const int ln = tid & 63;
    const int wr = w >> 1, wc = w & 1;
    const int n0g = blockIdx.x * 128;
    const int m0 = blockIdx.y * 128;

    // staging geometry: lane ln writes LDS chunk (row rb+srow, phys chunk ln&7);
    // load logical chunk scc = (ln&7) ^ srow from global (pre-swizzle)
    const int srow = ln >> 3;
    const int scc = (ln & 7) ^ srow;

    f32x4 acc[4][4];
#pragma unroll
    for (int i = 0; i < 4; ++i)
#pragma unroll
        for (int j = 0; j < 4; ++j) acc[i][j] = (f32x4){0.f, 0.f, 0.f, 0.f};

    // per-lane global bases (without k)
    const ushort_t* gAbase = Ap + (size_t)(m0 + w * 32 + srow) * KP3 + scc * 8;
    const ushort_t* gBbase = Bp + (size_t)(n0g + w * 32 + srow) * KP3 + scc * 8;

    for (int kt = 0; kt < 48; ++kt) {
        const int k0 = kt * 64;
        __syncthreads();
#pragma unroll
        for (int s = 0; s < 4; ++s) {
            const ushort_t* gA = gAbase + (size_t)(s * 8) * KP3 + k0;
            __builtin_amdgcn_global_load_lds(
                (const __attribute__((address_space(1))) void*)gA,
                (__attribute__((address_space(3))) void*)&As[(w * 32 + s * 8) * 64],
                16, 0, 0);
        }
#pragma unroll
        for (int s = 0; s < 4; ++s) {
            const ushort_t* gB = gBbase + (size_t)(s * 8) * KP3 + k0;
            __builtin_amdgcn_global_load_lds(
                (const __attribute__((address_space(1))) void*)gB,
                (__attribute__((address_space(3))) void*)&Bs[(w * 32 + s * 8) * 64],
                16, 0, 0);
        }
        __syncthreads();   // compiler drains vmcnt before s_barrier

#pragma unroll
        for (int kk = 0; kk < 2; ++kk) {
            bf16x8 af[4], bff[4];
#pragma unroll
            for (int mf = 0; mf < 4; ++mf) {
                const int row = wr * 64 + mf * 16 + (ln & 15);
                const int ch = ((kk * 4 + (ln >> 4)) ^ (ln & 7));
                af[mf] = *(const bf16x8*)((const char*)As + row * 128 + ch * 16);
            }
#pragma unroll
            for (int nf = 0; nf < 4; ++nf) {
                const int row = wc * 64 + nf * 16 + (ln & 15);
                const int ch = ((kk * 4 + (ln >> 4)) ^ (ln & 7));
                bff[nf] = *(const bf16x8*)((const char*)Bs + row * 128 + ch * 16);
            }
#pragma unroll
            for (int mf = 0; mf < 4; ++mf)
#pragma unroll
                for (int nf = 0; nf < 4; ++nf)
                    acc[mf][nf] = __builtin_amdgcn_mfma_f32_16x16x32_bf16(
                        af[mf], bff[nf], acc[mf][nf], 0, 0, 0);
        }
    }

    // epilogue: C/D layout col = ln&15, row = (ln>>4)*4 + j  [m89/m91 verified]
    if (mode == 0) {
#pragma unroll
        for (int mf = 0; mf < 4; ++mf)
#pragma unroll
            for (int nf = 0; nf < 4; ++nf)
#pragma unroll
                for (int j = 0; j < 4; ++j) {
                    const int m = m0 + wr * 64 + mf * 16 + (ln >> 4) * 4 + j;
                    const int n = n0g + wc * 64 + nf * 16 + (ln & 15);
                    outp[(size_t)m * D + n] = acc[mf][nf][j];
                }
    } else {
        const int which = n0g >> 10;               // 0=Q 1=K 2=V
        float* dst = (which == 0) ? qb : ((which == 1) ? kb : vb);
#pragma unroll
        for (int mf = 0; mf < 4; ++mf)
#pragma unroll
            for (int nf = 0; nf < 4; ++nf)
#pragma unroll
                for (int j = 0; j < 4; ++j) {
                    const int m = m0 + wr * 64 + mf * 16 + (ln >> 4) * 4 + j;
                    const int n = (n0g & 1023) + wc * 64 + nf * 16 + (ln & 15);
                    const int bb = m >> 11;
                    const int l = m & (L - 1);
                    const int h = n >> 6;
                    const int hd = n & 63;
                    float v = acc[mf][nf][j];
                    if (which < 2) {
                        const int ip = hd >> 1;
                        const float c = rc[l * (HD / 2) + ip];
                        const float s = rs[l * (HD / 2) + ip];
                        const float p = __shfl_xor(v, 1);
                        v = (hd & 1) ? fmaf(p, s, v * c) : fmaf(p, -s, v * c);
                    }
                    dst[(((size_t)(bb * H + h)) * L + l) * HD + hd] = v;
                }
    }
}

// ---------------- sliding-window attention ----------------
#define QT 64
#define KR (QT + W - 1)    // 95
#define KPAD 68            // stride 68 -> rotate effect, conflict-free reads

__global__ __launch_bounds__(64) void attn_kernel(
    const float* __restrict__ qb, const float* __restrict__ kb,
    const float* __restrict__ vb, const float* __restrict__ conn,
    ushort_t* __restrict__ aop)
{
    __shared__ float Ks[KR][KPAD];
    __shared__ float Vs[KR][KPAD];
    const int tid = threadIdx.x;
    const int l0 = blockIdx.x * QT;
    const int bh = blockIdx.y;
    const int h = bh & (H - 1);
    const int bb = bh >> 4;
    const float* Qg = qb + (size_t)bh * L * HD;
    const float* Kg = kb + (size_t)bh * L * HD;
    const float* Vg = vb + (size_t)bh * L * HD;

    for (int idx = tid; idx < KR * 16; idx += 64) {
        const int rr = idx >> 4;
        const int f4 = (idx & 15) << 2;
        const int lr = l0 - (W - 1) + rr;
        float4 kv = make_float4(0, 0, 0, 0);
        float4 vv = make_float4(0, 0, 0, 0);
        if (lr >= 0) {
            kv = *(const float4*)(Kg + (size_t)lr * HD + f4);
            vv = *(const float4*)(Vg + (size_t)lr * HD + f4);
        }
        *(float4*)&Ks[rr][f4] = kv;
        *(float4*)&Vs[rr][f4] = vv;
    }
    __syncthreads();

    const int l = l0 + tid;
    float4 q[16];
#pragma unroll
    for (int i = 0; i < 16; ++i) q[i] = *(const float4*)(Qg + (size_t)l * HD + i * 4);

    float sc[W];
#pragma unroll
    for (int w = 0; w < W; ++w) {
        const float* kr = Ks[tid + w];
        float s = 0.f;
#pragma unroll
        for (int i = 0; i < 16; ++i) {
            const float4 kv = *(const float4*)(kr + i * 4);
            s = fmaf(q[i].x, kv.x, s);
            s = fmaf(q[i].y, kv.y, s);
            s = fmaf(q[i].z, kv.z, s);
            s = fmaf(q[i].w, kv.w, s);
        }
        sc[w] = s * 0.125f;
    }

    float mx = -1e30f;
#pragma unroll
    for (int w = 0; w < W; ++w) mx = fmaxf(mx, sc[w]);
    float den = 0.f;
#pragma unroll
    for (int w = 0; w < W; ++w) { sc[w] = expf(sc[w] - mx); den += sc[w]; }
    const float inv = 1.f / den;
    float fsum = 0.f;
#pragma unroll
    for (int w = 0; w < W; ++w) {
        sc[w] = sc[w] * inv * conn[h * W + w];
        fsum += sc[w];
    }
    const float rn = 1.f / (fsum + 1e-9f);

    float4 o[16];
#pragma unroll
    for (int i = 0; i < 16; ++i) o[i] = make_float4(0, 0, 0, 0);
#pragma unroll
    for (int w = 0; w < W; ++w) {
        const float wt = sc[w] * rn;
        const float* vr = Vs[tid + w];
#pragma unroll
        for (int i = 0; i < 16; ++i) {
            const float4 vv = *(const float4*)(vr + i * 4);
            o[i].x = fmaf(wt, vv.x, o[i].x);
            o[i].y = fmaf(wt, vv.y, o[i].y);
            o[i].z = fmaf(wt, vv.z, o[i].z);
            o[i].w = fmaf(wt, vv.w, o[i].w);
        }
    }

    // write packed A-side rows [hi | lo | hi] for the out-projection GEMM
    const int m = bb * L + l;
    ushort_t* dp = aop + (size_t)m * KP3 + h * HD;
#pragma unroll
    for (int i = 0; i < 16; ++i) {
        float f[4] = {o[i].x, o[i].y, o[i].z, o[i].w};
        unsigned short hh[4], lo[4];
#pragma unroll
        for (int j = 0; j < 4; ++j) {
            hh[j] = f2bf(f[j]);
            lo[j] = f2bf(f[j] - bf2f(hh[j]));
        }
        uint2 hv = make_uint2(pk2(hh[0], hh[1]), pk2(hh[2], hh[3]));
        uint2 lv = make_uint2(pk2(lo[0], lo[1]), pk2(lo[2], lo[3]));
        *(uint2*)(dp + i * 4)            = hv;
        *(uint2*)(dp + D + i * 4)        = lv;
        *(uint2*)(dp + 2 * D + i * 4)    = hv;
    }
}

// ---------------- launcher ----------------
extern "C" void kernel_launch(void* const* d_in, const int* in_sizes, int n_in,
                              void* d_out, int out_size, void* d_ws, size_t ws_size,
                              hipStream_t stream)
{
    const float* x   = (const float*)d_in[0];
    const float* wq  = (const float*)d_in[1];
    const float* wk  = (const float*)d_in[2];
    const float* wv  = (const float*)d_in[3];
    const float* wo  = (const float*)d_in[4];
    const float* cw1 = (const float*)d_in[5];
    const float* cw2 = (const float*)d_in[6];
    const float* cw3 = (const float*)d_in[7];
    const float* rc  = (const float*)d_in[8];
    const float* rs  = (const float*)d_in[9];
    float* out = (float*)d_out;

    float* ws = (float*)d_ws;
    float* conn = ws;                                  // 512 floats (pad to 1024)
    float* qb = ws + 1024;                             // [B*H][L][HD] fp32
    float* kb = qb + (size_t)B * H * L * HD;
    float* vb = kb + (size_t)B * H * L * HD;
    ushort_t* xp    = (ushort_t*)(vb + (size_t)B * H * L * HD);  // [M][3072] bf16 (reused as aop)
    ushort_t* wqkvp = xp + (size_t)M * KP3;            // [3072][3072] bf16
    ushort_t* wop   = wqkvp + (size_t)3072 * KP3;      // [1024][3072] bf16

    pack_x_kernel<<<dim3(M * 128 / 256), dim3(256), 0, stream>>>(x, xp);
    pack_w_kernel<<<dim3(3072 * 128 / 256), dim3(256), 0, stream>>>(wq, wk, wv, wqkvp, 3072);
    pack_w_kernel<<<dim3(1024 * 128 / 256), dim3(256), 0, stream>>>(wo, wo, wo, wop, 1024);
    conn_kernel<<<dim3(1), dim3(512), 0, stream>>>(cw1, cw2, cw3, conn);

    gemm_split<<<dim3(24, 32), dim3(256), 0, stream>>>(
        xp, wqkvp, 1, nullptr, qb, kb, vb, rc, rs);

    attn_kernel<<<dim3(L / QT, B * H), dim3(64), 0, stream>>>(qb, kb, vb, conn, xp);

    gemm_split<<<dim3(8, 32), dim3(256), 0, stream>>>(
        xp, wop, 0, out, nullptr, nullptr, nullptr, rc, rs);
}